// Round 3
// baseline (196.311 us; speedup 1.0000x reference)
//
#include <hip/hip_runtime.h>

#define D 256
#define S 128
#define B 32
#define RT1 8     // rows per block in k1
#define DC 16     // d-chunk per block in k2

__device__ __forceinline__ float dot4(float4 a, float4 b) {
    return a.x * b.x + a.y * b.y + a.z * b.z + a.w * b.w;
}

// K1: C[row, n] = sum_k A[row,k] * W'[n,k] + b'[n], n in [0,512):
//     n<256 -> Wl/bl -> Xl ; n>=256 -> Wr/br -> Xr.
// Block: 8 rows x 512 n. Thread: 4 rows x 4 consecutive n (16 acc).
// A staged in LDS (8 KB), read as wave-broadcast ds_read_b128.
// W: 4 independent per-thread float4 streams from L1/L2 (W read once/block).
// Per k-step/thread: 4 global f4 + 4 broadcast ds f4 + 64 FMA.
__global__ __launch_bounds__(256) void k1_gemm(
    const int* __restrict__ X, const float* __restrict__ emb,
    const float* __restrict__ Wl, const float* __restrict__ bl,
    const float* __restrict__ Wr, const float* __restrict__ br,
    float* __restrict__ Xl, float* __restrict__ Xr)
{
    __shared__ float4 As[RT1][D / 4];   // 8 rows x 64 float4 = 8 KB

    const int tid = threadIdx.x;
    const int rowBase = blockIdx.x * RT1;

    // stage A: 512 float4, 2 per thread, coalesced within each row
#pragma unroll
    for (int t = 0; t < 2; ++t) {
        const int f = tid + t * 256;      // f = r*64 + kf
        const int r = f >> 6, kf = f & 63;
        const int tok = X[rowBase + r];   // block-uniform -> s_load
        As[r][kf] = ((const float4*)(emb + (size_t)tok * D))[kf];
    }
    __syncthreads();

    const int rg = tid >> 7;              // 0..1 : rows rg*4 .. rg*4+3
    const int nl = tid & 127;             // n = nl*4 .. nl*4+3
    const int n0 = nl * 4;
    const bool left = (n0 < 256);
    const float* __restrict__ Wbase = left ? (Wl + (size_t)n0 * D)
                                           : (Wr + (size_t)(n0 - 256) * D);
    const float4* __restrict__ w40 = (const float4*)(Wbase);
    const float4* __restrict__ w41 = (const float4*)(Wbase + D);
    const float4* __restrict__ w42 = (const float4*)(Wbase + 2 * D);
    const float4* __restrict__ w43 = (const float4*)(Wbase + 3 * D);

    float acc[4][4];
#pragma unroll
    for (int r = 0; r < 4; ++r)
#pragma unroll
        for (int n = 0; n < 4; ++n) acc[r][n] = 0.f;

#pragma unroll 4
    for (int kk = 0; kk < D / 4; ++kk) {
        float4 w0 = w40[kk], w1 = w41[kk], w2 = w42[kk], w3 = w43[kk];
        float4 a0 = As[rg * 4 + 0][kk];
        float4 a1 = As[rg * 4 + 1][kk];
        float4 a2 = As[rg * 4 + 2][kk];
        float4 a3 = As[rg * 4 + 3][kk];
        acc[0][0] += dot4(a0, w0); acc[0][1] += dot4(a0, w1);
        acc[0][2] += dot4(a0, w2); acc[0][3] += dot4(a0, w3);
        acc[1][0] += dot4(a1, w0); acc[1][1] += dot4(a1, w1);
        acc[1][2] += dot4(a1, w2); acc[1][3] += dot4(a1, w3);
        acc[2][0] += dot4(a2, w0); acc[2][1] += dot4(a2, w1);
        acc[2][2] += dot4(a2, w2); acc[2][3] += dot4(a2, w3);
        acc[3][0] += dot4(a3, w0); acc[3][1] += dot4(a3, w1);
        acc[3][2] += dot4(a3, w2); acc[3][3] += dot4(a3, w3);
    }

    const float* __restrict__ bsrc = left ? (bl + n0) : (br + (n0 - 256));
    const float4 bias = *(const float4*)bsrc;
    float* __restrict__ Obase = left ? (Xl + n0) : (Xr + (n0 - 256));

#pragma unroll
    for (int r = 0; r < 4; ++r) {
        const int row = rowBase + rg * 4 + r;
        float4 v;
        v.x = acc[r][0] + bias.x; v.y = acc[r][1] + bias.y;
        v.z = acc[r][2] + bias.z; v.w = acc[r][3] + bias.w;
        *(float4*)(Obase + (size_t)row * D) = v;   // coalesced
    }
}

// K2: pooled[b,d] = 0.5*( S*(sum_j xl + sum_i xr) + sum_{ij}|xl_j + xr_i| )
__global__ __launch_bounds__(256) void k2_pairsum(
    const float* __restrict__ Xl, const float* __restrict__ Xr,
    float* __restrict__ pooled)
{
    __shared__ float lxl[S * DC];   // [j][dl] : 8 KB
    __shared__ float lxr[S * DC];
    __shared__ float red[256];

    const int b   = blockIdx.x >> 4;
    const int dc  = blockIdx.x & 15;
    const int tid = threadIdx.x;
    const int dl  = tid & (DC - 1);
    const int ig  = tid >> 4;          // 0..15, 8 i's each

    const size_t base = (size_t)b * S * D + (size_t)dc * DC;
    {
        float4* lxl4 = (float4*)lxl;
        float4* lxr4 = (float4*)lxr;
#pragma unroll
        for (int t = 0; t < 2; ++t) {
            const int e4 = tid + t * 256;       // e4 = j*4 + df
            const int j = e4 >> 2, df = e4 & 3;
            const float4* pl = (const float4*)(Xl + base + (size_t)j * D);
            const float4* pr = (const float4*)(Xr + base + (size_t)j * D);
            lxl4[e4] = pl[df];
            lxr4[e4] = pr[df];
        }
    }
    __syncthreads();

    float xr[8];
    float sr = 0.f;
#pragma unroll
    for (int u = 0; u < 8; ++u) {
        xr[u] = lxr[(ig * 8 + u) * DC + dl];
        sr += xr[u];
    }

    float sabs = 0.f, sxl = 0.f;
#pragma unroll 4
    for (int j = 0; j < S; ++j) {
        const float x = lxl[j * DC + dl];
        sxl += x;
#pragma unroll
        for (int u = 0; u < 8; ++u)
            sabs += fabsf(x + xr[u]);
    }

    red[tid] = sabs + (float)S * sr;
    __syncthreads();

    if (tid < DC) {
        float tot = 0.f;
#pragma unroll
        for (int g = 0; g < 16; ++g) tot += red[g * DC + tid];
        pooled[(size_t)b * D + (size_t)dc * DC + tid] =
            0.5f * ((float)S * sxl + tot);
    }
}

// K3: out[b,d] = sum_k pooled[b,k]*Wrn[d,k] + S*S*brn[d]
__global__ __launch_bounds__(256) void k3_out(
    const float* __restrict__ pooled, const float* __restrict__ Wrn,
    const float* __restrict__ brn, float* __restrict__ out)
{
    __shared__ float lp[D];
    __shared__ float red[256];
    const int bb = blockIdx.x >> 3;
    const int dc = blockIdx.x & 7;
    const int tid = threadIdx.x;
    lp[tid] = pooled[(size_t)bb * D + tid];
    __syncthreads();

    const int dl = tid & 31;
    const int kg = tid >> 5;
    const int d = dc * 32 + dl;
    const float4* __restrict__ w4 = (const float4*)(Wrn + (size_t)d * D) + kg * 8;
    const float4* __restrict__ p4 = (const float4*)lp + kg * 8;
    float acc = 0.f;
#pragma unroll
    for (int f = 0; f < 8; ++f) acc += dot4(w4[f], p4[f]);

    red[tid] = acc;
    __syncthreads();
    if (tid < 32) {
        float s = 0.f;
#pragma unroll
        for (int g = 0; g < 8; ++g) s += red[g * 32 + tid];
        out[(size_t)bb * D + dc * 32 + tid] = s + (float)(S * S) * brn[dc * 32 + tid];
    }
}

extern "C" void kernel_launch(void* const* d_in, const int* in_sizes, int n_in,
                              void* d_out, int out_size, void* d_ws, size_t ws_size,
                              hipStream_t stream) {
    const int*   X   = (const int*)d_in[0];
    const float* emb = (const float*)d_in[1];
    const float* Wl  = (const float*)d_in[2];
    const float* bl  = (const float*)d_in[3];
    const float* Wr  = (const float*)d_in[4];
    const float* br  = (const float*)d_in[5];
    const float* Wrn = (const float*)d_in[6];
    const float* brn = (const float*)d_in[7];
    float* out = (float*)d_out;

    float* ws     = (float*)d_ws;
    float* Xl     = ws;                         // 1M floats
    float* Xr     = ws + (size_t)B * S * D;     // 1M floats
    float* pooled = ws + 2 * (size_t)B * S * D; // 8192 floats

    k1_gemm<<<(B * S) / RT1, 256, 0, stream>>>(X, emb, Wl, bl, Wr, br, Xl, Xr);
    k2_pairsum<<<B * (D / DC), 256, 0, stream>>>(Xl, Xr, pooled);
    k3_out<<<B * 8, 256, 0, stream>>>(pooled, Wrn, brn, out);
}

// Round 4
// 185.331 us; speedup vs baseline: 1.0592x; 1.0592x over previous
//
#include <hip/hip_runtime.h>

#define D 256
#define S 128
#define B 32
#define DC 16     // d-chunk per block in k2

__device__ __forceinline__ float dot4(float4 a, float4 b) {
    return a.x * b.x + a.y * b.y + a.z * b.z + a.w * b.w;
}

// K1: C[row, n] = sum_k A[row,k]*W'[n,k] + b'[n], n in [0,512):
//   n<256 -> Wl/bl -> Xl ; n>=256 -> Wr/br -> Xr.
// Block: 8 rows x 512 n, grid 512 (2 blocks/CU). K in 8 chunks of 32.
// W staged via LDS: global loads are 8 rows x 128 B contiguous per wave
// (full 64-B lines); LDS fragment layout Wf[kk][half][v][lane] gives
// lane-contiguous 16-B reads (conflict-free b128). Register double-buffer
// overlaps chunk c+1 loads with chunk c compute.
__global__ __launch_bounds__(256) void k1_gemm(
    const int* __restrict__ X, const float* __restrict__ emb,
    const float* __restrict__ Wl, const float* __restrict__ bl,
    const float* __restrict__ Wr, const float* __restrict__ br,
    float* __restrict__ Xl, float* __restrict__ Xr)
{
    __shared__ float4 As[8][64];        // 8 KB: A rows
    __shared__ float4 Wf[8 * 513];      // 64.1 KB: one 32-k chunk of all 512 W rows

    const int tid = threadIdx.x;
    const int rowBase = blockIdx.x * 8;

    // stage A once: 512 float4, coalesced per row
#pragma unroll
    for (int t = 0; t < 2; ++t) {
        const int f = tid + t * 256;      // f = r*64 + kf
        const int r = f >> 6, kf = f & 63;
        const int tok = X[rowBase + r];   // block-uniform
        As[r][kf] = ((const float4*)(emb + (size_t)tok * D))[kf];
    }

    const int kf_s = tid & 7;    // staging: f4 index within 128-B chunk
    const int rb_s = tid >> 3;   // staging: row base 0..31 (stride 32)
    const int rg   = tid >> 7;   // compute: row group 0..1 (rows rg*4..+3)
    const int l    = tid & 63;   // lane
    const int half = (tid >> 6) & 1;   // n-half: 0 -> Wl, 1 -> Wr

    // prefetch W chunk 0 into registers
    float4 tmp[16];
#pragma unroll
    for (int g = 0; g < 16; ++g) {
        const int n = rb_s + 32 * g;
        const float* Wrow = (n < 256) ? (Wl + (size_t)n * D)
                                      : (Wr + (size_t)(n - 256) * D);
        tmp[g] = ((const float4*)Wrow)[kf_s];
    }

    float acc[4][4];
#pragma unroll
    for (int r = 0; r < 4; ++r)
#pragma unroll
        for (int v = 0; v < 4; ++v) acc[r][v] = 0.f;

    for (int c = 0; c < 8; ++c) {
        __syncthreads();   // previous compute done; LDS (and As on c=0) safe to use
#pragma unroll
        for (int g = 0; g < 16; ++g) {
            const int n = rb_s + 32 * g;
            // Wf[kf][half=n>>8][v=n&3][lane=(n>>2)&63], slab stride 513
            Wf[513 * kf_s + 256 * (n >> 8) + 64 * (n & 3) + ((n >> 2) & 63)] = tmp[g];
        }
        __syncthreads();
        if (c < 7) {       // issue next chunk's loads before compute (overlap)
#pragma unroll
            for (int g = 0; g < 16; ++g) {
                const int n = rb_s + 32 * g;
                const float* Wrow = (n < 256) ? (Wl + (size_t)n * D)
                                              : (Wr + (size_t)(n - 256) * D);
                tmp[g] = ((const float4*)Wrow)[(c + 1) * 8 + kf_s];
            }
        }
#pragma unroll
        for (int kk = 0; kk < 8; ++kk) {
            const int wb = 513 * kk + 256 * half + l;
            const float4 w0 = Wf[wb];
            const float4 w1 = Wf[wb + 64];
            const float4 w2 = Wf[wb + 128];
            const float4 w3 = Wf[wb + 192];
#pragma unroll
            for (int r = 0; r < 4; ++r) {
                const float4 a = As[rg * 4 + r][c * 8 + kk];   // broadcast
                acc[r][0] += dot4(a, w0);
                acc[r][1] += dot4(a, w1);
                acc[r][2] += dot4(a, w2);
                acc[r][3] += dot4(a, w3);
            }
        }
    }

    // epilogue: thread owns n = half*256 + l*4 + v, rows rowBase+rg*4..+3
    const float4 bias = *(const float4*)((half ? br : bl) + l * 4);
    float* __restrict__ Obase = (half ? Xr : Xl) + l * 4;
#pragma unroll
    for (int r = 0; r < 4; ++r) {
        const int row = rowBase + rg * 4 + r;
        float4 v;
        v.x = acc[r][0] + bias.x; v.y = acc[r][1] + bias.y;
        v.z = acc[r][2] + bias.z; v.w = acc[r][3] + bias.w;
        *(float4*)(Obase + (size_t)row * D) = v;   // coalesced
    }
}

// K2: pooled[b,d] = 0.5*( S*(sum_j xl + sum_i xr) + sum_{ij}|xl_j + xr_i| )
__global__ __launch_bounds__(256) void k2_pairsum(
    const float* __restrict__ Xl, const float* __restrict__ Xr,
    float* __restrict__ pooled)
{
    __shared__ float lxl[S * DC];   // [j][dl] : 8 KB
    __shared__ float lxr[S * DC];
    __shared__ float red[256];

    const int b   = blockIdx.x >> 4;
    const int dc  = blockIdx.x & 15;
    const int tid = threadIdx.x;
    const int dl  = tid & (DC - 1);
    const int ig  = tid >> 4;          // 0..15, 8 i's each

    const size_t base = (size_t)b * S * D + (size_t)dc * DC;
    {
        float4* lxl4 = (float4*)lxl;
        float4* lxr4 = (float4*)lxr;
#pragma unroll
        for (int t = 0; t < 2; ++t) {
            const int e4 = tid + t * 256;       // e4 = j*4 + df
            const int j = e4 >> 2, df = e4 & 3;
            const float4* pl = (const float4*)(Xl + base + (size_t)j * D);
            const float4* pr = (const float4*)(Xr + base + (size_t)j * D);
            lxl4[e4] = pl[df];
            lxr4[e4] = pr[df];
        }
    }
    __syncthreads();

    float xr[8];
    float sr = 0.f;
#pragma unroll
    for (int u = 0; u < 8; ++u) {
        xr[u] = lxr[(ig * 8 + u) * DC + dl];
        sr += xr[u];
    }

    float sabs = 0.f, sxl = 0.f;
#pragma unroll 4
    for (int j = 0; j < S; ++j) {
        const float x = lxl[j * DC + dl];
        sxl += x;
#pragma unroll
        for (int u = 0; u < 8; ++u)
            sabs += fabsf(x + xr[u]);
    }

    red[tid] = sabs + (float)S * sr;
    __syncthreads();

    if (tid < DC) {
        float tot = 0.f;
#pragma unroll
        for (int g = 0; g < 16; ++g) tot += red[g * DC + tid];
        pooled[(size_t)b * D + (size_t)dc * DC + tid] =
            0.5f * ((float)S * sxl + tot);
    }
}

// K3: out[b,d] = sum_k pooled[b,k]*Wrn[d,k] + S*S*brn[d]
__global__ __launch_bounds__(256) void k3_out(
    const float* __restrict__ pooled, const float* __restrict__ Wrn,
    const float* __restrict__ brn, float* __restrict__ out)
{
    __shared__ float lp[D];
    __shared__ float red[256];
    const int bb = blockIdx.x >> 3;
    const int dc = blockIdx.x & 7;
    const int tid = threadIdx.x;
    lp[tid] = pooled[(size_t)bb * D + tid];
    __syncthreads();

    const int dl = tid & 31;
    const int kg = tid >> 5;
    const int d = dc * 32 + dl;
    const float4* __restrict__ w4 = (const float4*)(Wrn + (size_t)d * D) + kg * 8;
    const float4* __restrict__ p4 = (const float4*)lp + kg * 8;
    float acc = 0.f;
#pragma unroll
    for (int f = 0; f < 8; ++f) acc += dot4(w4[f], p4[f]);

    red[tid] = acc;
    __syncthreads();
    if (tid < 32) {
        float s = 0.f;
#pragma unroll
        for (int g = 0; g < 8; ++g) s += red[g * 32 + tid];
        out[(size_t)bb * D + dc * 32 + tid] = s + (float)(S * S) * brn[dc * 32 + tid];
    }
}

extern "C" void kernel_launch(void* const* d_in, const int* in_sizes, int n_in,
                              void* d_out, int out_size, void* d_ws, size_t ws_size,
                              hipStream_t stream) {
    const int*   X   = (const int*)d_in[0];
    const float* emb = (const float*)d_in[1];
    const float* Wl  = (const float*)d_in[2];
    const float* bl  = (const float*)d_in[3];
    const float* Wr  = (const float*)d_in[4];
    const float* br  = (const float*)d_in[5];
    const float* Wrn = (const float*)d_in[6];
    const float* brn = (const float*)d_in[7];
    float* out = (float*)d_out;

    float* ws     = (float*)d_ws;
    float* Xl     = ws;                         // 1M floats
    float* Xr     = ws + (size_t)B * S * D;     // 1M floats
    float* pooled = ws + 2 * (size_t)B * S * D; // 8192 floats

    k1_gemm<<<(B * S) / 8, 256, 0, stream>>>(X, emb, Wl, bl, Wr, br, Xl, Xr);
    k2_pairsum<<<B * (D / DC), 256, 0, stream>>>(Xl, Xr, pooled);
    k3_out<<<B * 8, 256, 0, stream>>>(pooled, Wrn, brn, out);
}

// Round 5
// 133.482 us; speedup vs baseline: 1.4707x; 1.3884x over previous
//
#include <hip/hip_runtime.h>

#define D 256
#define S 128
#define B 32
#define DC 16     // d-chunk per block in k2

__device__ __forceinline__ float dot4(float4 a, float4 b) {
    return a.x * b.x + a.y * b.y + a.z * b.z + a.w * b.w;
}

// K0: Wt[k][n] = (n<256 ? Wl[n][k] : Wr[n-256][k]), Wt is 256 x 512 (512 KB).
// LDS 32x64 tile transpose; fully coalesced global read and write.
__global__ __launch_bounds__(256) void k0_transpose(
    const float* __restrict__ Wl, const float* __restrict__ Wr,
    float* __restrict__ Wt)
{
    __shared__ float t[32][65];            // [k_local][n_local], padded
    const int tid = threadIdx.x;
    const int bk = blockIdx.x & 7;         // k-tile
    const int bn = blockIdx.x >> 3;        // n-tile
    const int k0 = bk * 32, n0 = bn * 64;
    const float* __restrict__ Wsrc = (n0 < 256)
        ? (Wl + (size_t)n0 * D) : (Wr + (size_t)(n0 - 256) * D);

    const int tx = tid & 31;               // k offset
    const int ty = tid >> 5;               // 0..7
#pragma unroll
    for (int j = 0; j < 8; ++j) {
        const int nl = ty + j * 8;         // 0..63
        t[tx][nl] = Wsrc[(size_t)nl * D + k0 + tx];   // 2x128B rows per wave
    }
    __syncthreads();

    const int nl2 = tid & 63;              // coalesced 256 B per wave
    const int kl2 = tid >> 6;              // 0..3
#pragma unroll
    for (int j = 0; j < 8; ++j) {
        const int kl = kl2 + j * 4;
        Wt[(size_t)(k0 + kl) * 512 + n0 + nl2] = t[kl][nl2];
    }
}

// K1: C[row, n] = sum_k A[row,k] * Wt[k,n] + b'[n], n in [0,512).
// Block: 8 rows x 512 n, grid 512 (2 blocks/CU). Thread: 4 rows x 4 n.
// Per 4-k group: 4 coalesced global float4 (Wt rows, full-line, read once
// per block), 4 broadcast ds_read_b128 (A), 64 FMA. One-group software
// prefetch; ~65 VGPR, no spills, no W staging syncs.
__global__ __launch_bounds__(256) void k1_gemm(
    const int* __restrict__ X, const float* __restrict__ emb,
    const float* __restrict__ Wt,
    const float* __restrict__ bl, const float* __restrict__ br,
    float* __restrict__ Xl, float* __restrict__ Xr)
{
    __shared__ float4 As[8][64];           // 8 KB

    const int tid = threadIdx.x;
    const int rowBase = blockIdx.x * 8;

#pragma unroll
    for (int t = 0; t < 2; ++t) {
        const int f = tid + t * 256;       // f = r*64 + kf
        const int r = f >> 6, kf = f & 63;
        const int tok = X[rowBase + r];    // block-uniform
        As[r][kf] = ((const float4*)(emb + (size_t)tok * D))[kf];
    }
    __syncthreads();

    const int rg = tid >> 7;               // rows rg*4 .. rg*4+3
    const int nl = tid & 127;              // n0 = nl*4
    const float4* __restrict__ wt4 = (const float4*)Wt + nl;  // + k*128

    float acc[4][4];
#pragma unroll
    for (int r = 0; r < 4; ++r)
#pragma unroll
        for (int v = 0; v < 4; ++v) acc[r][v] = 0.f;

    float4 w[4];
#pragma unroll
    for (int u = 0; u < 4; ++u) w[u] = wt4[(size_t)u * 128];

#define K1_COMPUTE(g)                                                        \
    {                                                                        \
        const float* w0 = (const float*)&w[0];                               \
        const float* w1 = (const float*)&w[1];                               \
        const float* w2 = (const float*)&w[2];                               \
        const float* w3 = (const float*)&w[3];                               \
        _Pragma("unroll")                                                    \
        for (int r = 0; r < 4; ++r) {                                        \
            const float4 a = As[rg * 4 + r][g];                              \
            _Pragma("unroll")                                                \
            for (int v = 0; v < 4; ++v)                                      \
                acc[r][v] += a.x * w0[v] + a.y * w1[v]                       \
                           + a.z * w2[v] + a.w * w3[v];                      \
        }                                                                    \
    }

    for (int g = 0; g < 63; ++g) {
        float4 wn[4];
#pragma unroll
        for (int u = 0; u < 4; ++u)
            wn[u] = wt4[(size_t)(4 * (g + 1) + u) * 128];
        K1_COMPUTE(g);
#pragma unroll
        for (int u = 0; u < 4; ++u) w[u] = wn[u];
    }
    K1_COMPUTE(63);
#undef K1_COMPUTE

    // thread owns n = nl*4 .. nl*4+3 ; half = nl>>6 (wave-uniform)
    const int half = nl >> 6;
    const int col = (nl & 63) * 4;
    const float4 bias = *(const float4*)((half ? br : bl) + col);
    float* __restrict__ Obase = (half ? Xr : Xl) + col;
#pragma unroll
    for (int r = 0; r < 4; ++r) {
        const int row = rowBase + rg * 4 + r;
        float4 v;
        v.x = acc[r][0] + bias.x; v.y = acc[r][1] + bias.y;
        v.z = acc[r][2] + bias.z; v.w = acc[r][3] + bias.w;
        *(float4*)(Obase + (size_t)row * D) = v;   // coalesced 1 KB/wave
    }
}

// K2: pooled[b,d] = 0.5*( S*(sum_j xl + sum_i xr) + sum_{ij}|xl_j + xr_i| )
__global__ __launch_bounds__(256) void k2_pairsum(
    const float* __restrict__ Xl, const float* __restrict__ Xr,
    float* __restrict__ pooled)
{
    __shared__ float lxl[S * DC];   // [j][dl] : 8 KB
    __shared__ float lxr[S * DC];
    __shared__ float red[256];

    const int b   = blockIdx.x >> 4;
    const int dc  = blockIdx.x & 15;
    const int tid = threadIdx.x;
    const int dl  = tid & (DC - 1);
    const int ig  = tid >> 4;          // 0..15, 8 i's each

    const size_t base = (size_t)b * S * D + (size_t)dc * DC;
    {
        float4* lxl4 = (float4*)lxl;
        float4* lxr4 = (float4*)lxr;
#pragma unroll
        for (int t = 0; t < 2; ++t) {
            const int e4 = tid + t * 256;       // e4 = j*4 + df
            const int j = e4 >> 2, df = e4 & 3;
            const float4* pl = (const float4*)(Xl + base + (size_t)j * D);
            const float4* pr = (const float4*)(Xr + base + (size_t)j * D);
            lxl4[e4] = pl[df];
            lxr4[e4] = pr[df];
        }
    }
    __syncthreads();

    float xr[8];
    float sr = 0.f;
#pragma unroll
    for (int u = 0; u < 8; ++u) {
        xr[u] = lxr[(ig * 8 + u) * DC + dl];
        sr += xr[u];
    }

    float sabs = 0.f, sxl = 0.f;
#pragma unroll 4
    for (int j = 0; j < S; ++j) {
        const float x = lxl[j * DC + dl];
        sxl += x;
#pragma unroll
        for (int u = 0; u < 8; ++u)
            sabs += fabsf(x + xr[u]);
    }

    red[tid] = sabs + (float)S * sr;
    __syncthreads();

    if (tid < DC) {
        float tot = 0.f;
#pragma unroll
        for (int g = 0; g < 16; ++g) tot += red[g * DC + tid];
        pooled[(size_t)b * D + (size_t)dc * DC + tid] =
            0.5f * ((float)S * sxl + tot);
    }
}

// K3: out[b,d] = sum_k pooled[b,k]*Wrn[d,k] + S*S*brn[d]
__global__ __launch_bounds__(256) void k3_out(
    const float* __restrict__ pooled, const float* __restrict__ Wrn,
    const float* __restrict__ brn, float* __restrict__ out)
{
    __shared__ float lp[D];
    __shared__ float red[256];
    const int bb = blockIdx.x >> 3;
    const int dc = blockIdx.x & 7;
    const int tid = threadIdx.x;
    lp[tid] = pooled[(size_t)bb * D + tid];
    __syncthreads();

    const int dl = tid & 31;
    const int kg = tid >> 5;
    const int d = dc * 32 + dl;
    const float4* __restrict__ w4 = (const float4*)(Wrn + (size_t)d * D) + kg * 8;
    const float4* __restrict__ p4 = (const float4*)lp + kg * 8;
    float acc = 0.f;
#pragma unroll
    for (int f = 0; f < 8; ++f) acc += dot4(w4[f], p4[f]);

    red[tid] = acc;
    __syncthreads();
    if (tid < 32) {
        float s = 0.f;
#pragma unroll
        for (int g = 0; g < 8; ++g) s += red[g * 32 + tid];
        out[(size_t)bb * D + dc * 32 + tid] = s + (float)(S * S) * brn[dc * 32 + tid];
    }
}

extern "C" void kernel_launch(void* const* d_in, const int* in_sizes, int n_in,
                              void* d_out, int out_size, void* d_ws, size_t ws_size,
                              hipStream_t stream) {
    const int*   X   = (const int*)d_in[0];
    const float* emb = (const float*)d_in[1];
    const float* Wl  = (const float*)d_in[2];
    const float* bl  = (const float*)d_in[3];
    const float* Wr  = (const float*)d_in[4];
    const float* br  = (const float*)d_in[5];
    const float* Wrn = (const float*)d_in[6];
    const float* brn = (const float*)d_in[7];
    float* out = (float*)d_out;

    float* ws     = (float*)d_ws;
    float* Xl     = ws;                          // 1M floats
    float* Xr     = ws + (size_t)B * S * D;      // 1M floats
    float* pooled = ws + 2 * (size_t)B * S * D;  // 8192 floats
    float* Wt     = pooled + B * D;              // 256*512 = 128K floats

    k0_transpose<<<64, 256, 0, stream>>>(Wl, Wr, Wt);
    k1_gemm<<<(B * S) / 8, 256, 0, stream>>>(X, emb, Wt, bl, br, Xl, Xr);
    k2_pairsum<<<B * (D / DC), 256, 0, stream>>>(Xl, Xr, pooled);
    k3_out<<<B * 8, 256, 0, stream>>>(pooled, Wrn, brn, out);
}

// Round 6
// 112.725 us; speedup vs baseline: 1.7415x; 1.1841x over previous
//
#include <hip/hip_runtime.h>

#define D 256
#define S 128
#define B 32
#define DC 16

typedef __attribute__((ext_vector_type(8))) short bf16x8;
typedef __attribute__((ext_vector_type(4))) float f32x4;

__device__ __forceinline__ unsigned short f2bf(float f) {
    union { float f; unsigned u; } v; v.f = f;
    unsigned r = v.u + 0x7FFFu + ((v.u >> 16) & 1u);   // RNE
    return (unsigned short)(r >> 16);
}

__device__ __forceinline__ float dot4(float4 a, float4 b) {
    return a.x * b.x + a.y * b.y + a.z * b.z + a.w * b.w;
}

// K0: Wb[n][k] (bf16, 512x256) = n<256 ? Wl[n][k] : Wr[n-256][k].
// 4 elems/thread, fully coalesced.
__global__ __launch_bounds__(256) void k0_cast(
    const float* __restrict__ Wl, const float* __restrict__ Wr,
    unsigned short* __restrict__ Wb)
{
    const int idx = blockIdx.x * 256 + threadIdx.x;   // 32768 quads
    const int e = idx * 4;
    const int n = e >> 8, k = e & 255;
    const float* src = (n < 256) ? (Wl + (size_t)n * D + k)
                                 : (Wr + (size_t)(n - 256) * D + k);
    const float4 f = *(const float4*)src;
    ushort4 h;
    h.x = f2bf(f.x); h.y = f2bf(f.y); h.z = f2bf(f.z); h.w = f2bf(f.w);
    *(ushort4*)(Wb + (size_t)n * D + k) = h;
}

// K1 (MFMA): C[row,n] = sum_k Ae[row,k]*W'[n,k] + b'[n].
// Block: 16 m x 256 n (half = blockIdx&1), grid 512. 4 waves; wave w owns
// n = half*256 + w*64 .. +63 via 4 16x16 acc tiles; K = 8 MFMA steps.
// A: emb rows cast to bf16 in LDS, stride 264 (2-way bank alias = free).
//   A-frag: lane holds A[m=l&15][k=(l>>4)*8+j] -> ds_read_b128.
// B: W row-major bf16 IS the B-frag layout (B[k][n]=W[n][k], n=l&15,
//   k=(l>>4)*8+j -> 16 contiguous bytes of W row) -> global b128, L1/L2-hot.
// C/D: row=(l>>4)*4+reg, col=l&15 (verified layout).
__global__ __launch_bounds__(256) void k1_mfma(
    const int* __restrict__ X, const float* __restrict__ emb,
    const unsigned short* __restrict__ Wb,
    const float* __restrict__ bl, const float* __restrict__ br,
    float* __restrict__ Xl, float* __restrict__ Xr)
{
    constexpr int LDA = 264;
    __shared__ unsigned short Asb[16 * LDA];   // 8448 B

    const int tid = threadIdx.x;
    const int rowBase = (blockIdx.x >> 1) * 16;
    const int half = blockIdx.x & 1;

    // stage A: thread -> row r=tid>>4, 16 cols from c0=(tid&15)*16
    {
        const int r = tid >> 4;
        const int c0 = (tid & 15) * 16;
        const int tok = X[rowBase + r];                  // 16-thread uniform
        const float* src = emb + (size_t)tok * D + c0;   // 256 B/row-quarter
        unsigned short* dst = Asb + r * LDA + c0;
#pragma unroll
        for (int j4 = 0; j4 < 4; ++j4) {
            const float4 f = ((const float4*)src)[j4];
            ushort4 h;
            h.x = f2bf(f.x); h.y = f2bf(f.y); h.z = f2bf(f.z); h.w = f2bf(f.w);
            ((ushort4*)dst)[j4] = h;
        }
    }
    __syncthreads();

    const int w  = tid >> 6;        // wave 0..3
    const int l  = tid & 63;
    const int lm = l & 15;          // m (A) / n (B) within tile
    const int lq = l >> 4;          // quad 0..3

    const unsigned short* aptr = Asb + lm * LDA + lq * 8;
    const int n_base = half * 256 + w * 64;
    const unsigned short* bptr = Wb + (size_t)(n_base + lm) * D + lq * 8;

    f32x4 acc[4];
#pragma unroll
    for (int t = 0; t < 4; ++t) acc[t] = (f32x4){0.f, 0.f, 0.f, 0.f};

#pragma unroll
    for (int ks = 0; ks < 8; ++ks) {
        const bf16x8 a = *(const bf16x8*)(aptr + ks * 32);
#pragma unroll
        for (int t = 0; t < 4; ++t) {
            const bf16x8 b = *(const bf16x8*)(bptr + (size_t)t * 16 * D + ks * 32);
            acc[t] = __builtin_amdgcn_mfma_f32_16x16x32_bf16(a, b, acc[t], 0, 0, 0);
        }
    }

    const float* __restrict__ bias = half ? br : bl;
    float* __restrict__ Obase = half ? Xr : Xl;
#pragma unroll
    for (int t = 0; t < 4; ++t) {
        const int col = w * 64 + t * 16 + lm;       // 0..255 within half
        const float bv = bias[col];
#pragma unroll
        for (int i = 0; i < 4; ++i) {
            const int row = rowBase + lq * 4 + i;
            Obase[(size_t)row * D + col] = acc[t][i] + bv;   // 4x64B segs/instr
        }
    }
}

// K2: pooled[b,d] = 0.5*( S*(sum_j xl + sum_i xr) + sum_{ij}|xl_j + xr_i| )
__global__ __launch_bounds__(256) void k2_pairsum(
    const float* __restrict__ Xl, const float* __restrict__ Xr,
    float* __restrict__ pooled)
{
    __shared__ float lxl[S * DC];   // [j][dl] : 8 KB
    __shared__ float lxr[S * DC];
    __shared__ float red[256];

    const int b   = blockIdx.x >> 4;
    const int dc  = blockIdx.x & 15;
    const int tid = threadIdx.x;
    const int dl  = tid & (DC - 1);
    const int ig  = tid >> 4;          // 0..15, 8 i's each

    const size_t base = (size_t)b * S * D + (size_t)dc * DC;
    {
        float4* lxl4 = (float4*)lxl;
        float4* lxr4 = (float4*)lxr;
#pragma unroll
        for (int t = 0; t < 2; ++t) {
            const int e4 = tid + t * 256;       // e4 = j*4 + df
            const int j = e4 >> 2, df = e4 & 3;
            const float4* pl = (const float4*)(Xl + base + (size_t)j * D);
            const float4* pr = (const float4*)(Xr + base + (size_t)j * D);
            lxl4[e4] = pl[df];
            lxr4[e4] = pr[df];
        }
    }
    __syncthreads();

    float xr[8];
    float sr = 0.f;
#pragma unroll
    for (int u = 0; u < 8; ++u) {
        xr[u] = lxr[(ig * 8 + u) * DC + dl];
        sr += xr[u];
    }

    float sabs = 0.f, sxl = 0.f;
#pragma unroll 4
    for (int j = 0; j < S; ++j) {
        const float x = lxl[j * DC + dl];
        sxl += x;
#pragma unroll
        for (int u = 0; u < 8; ++u)
            sabs += fabsf(x + xr[u]);
    }

    red[tid] = sabs + (float)S * sr;
    __syncthreads();

    if (tid < DC) {
        float tot = 0.f;
#pragma unroll
        for (int g = 0; g < 16; ++g) tot += red[g * DC + tid];
        pooled[(size_t)b * D + (size_t)dc * DC + tid] =
            0.5f * ((float)S * sxl + tot);
    }
}

// K3: out[b,d] = sum_k pooled[b,k]*Wrn[d,k] + S*S*brn[d]
__global__ __launch_bounds__(256) void k3_out(
    const float* __restrict__ pooled, const float* __restrict__ Wrn,
    const float* __restrict__ brn, float* __restrict__ out)
{
    __shared__ float lp[D];
    __shared__ float red[256];
    const int bb = blockIdx.x >> 3;
    const int dc = blockIdx.x & 7;
    const int tid = threadIdx.x;
    lp[tid] = pooled[(size_t)bb * D + tid];
    __syncthreads();

    const int dl = tid & 31;
    const int kg = tid >> 5;
    const int d = dc * 32 + dl;
    const float4* __restrict__ w4 = (const float4*)(Wrn + (size_t)d * D) + kg * 8;
    const float4* __restrict__ p4 = (const float4*)lp + kg * 8;
    float acc = 0.f;
#pragma unroll
    for (int f = 0; f < 8; ++f) acc += dot4(w4[f], p4[f]);

    red[tid] = acc;
    __syncthreads();
    if (tid < 32) {
        float s = 0.f;
#pragma unroll
        for (int g = 0; g < 8; ++g) s += red[g * 32 + tid];
        out[(size_t)bb * D + dc * 32 + tid] = s + (float)(S * S) * brn[dc * 32 + tid];
    }
}

extern "C" void kernel_launch(void* const* d_in, const int* in_sizes, int n_in,
                              void* d_out, int out_size, void* d_ws, size_t ws_size,
                              hipStream_t stream) {
    const int*   X   = (const int*)d_in[0];
    const float* emb = (const float*)d_in[1];
    const float* Wl  = (const float*)d_in[2];
    const float* bl  = (const float*)d_in[3];
    const float* Wr  = (const float*)d_in[4];
    const float* br  = (const float*)d_in[5];
    const float* Wrn = (const float*)d_in[6];
    const float* brn = (const float*)d_in[7];
    float* out = (float*)d_out;

    float* ws     = (float*)d_ws;
    float* Xl     = ws;                            // 1M floats
    float* Xr     = ws + (size_t)B * S * D;        // 1M floats
    float* pooled = ws + 2 * (size_t)B * S * D;    // 8192 floats
    unsigned short* Wb = (unsigned short*)(pooled + B * D);  // 512x256 bf16

    k0_cast<<<128, 256, 0, stream>>>(Wl, Wr, Wb);
    k1_mfma<<<512, 256, 0, stream>>>(X, emb, Wb, bl, br, Xl, Xr);
    k2_pairsum<<<B * (D / DC), 256, 0, stream>>>(Xl, Xr, pooled);
    k3_out<<<B * 8, 256, 0, stream>>>(pooled, Wrn, brn, out);
}

// Round 7
// 111.904 us; speedup vs baseline: 1.7543x; 1.0073x over previous
//
#include <hip/hip_runtime.h>

#define D 256
#define S 128
#define B 32
#define DC 16

typedef __attribute__((ext_vector_type(8))) short bf16x8;
typedef __attribute__((ext_vector_type(4))) float f32x4;

__device__ __forceinline__ unsigned short f2bf(float f) {
    union { float f; unsigned u; } v; v.f = f;
    unsigned r = v.u + 0x7FFFu + ((v.u >> 16) & 1u);   // RNE
    return (unsigned short)(r >> 16);
}
__device__ __forceinline__ float bf2f(unsigned short h) {
    union { unsigned u; float f; } v; v.u = ((unsigned)h) << 16;
    return v.f;
}
__device__ __forceinline__ float dot4(float4 a, float4 b) {
    return a.x * b.x + a.y * b.y + a.z * b.z + a.w * b.w;
}

// K0: Wb[n][k] (bf16, 512x256) = n<256 ? Wl[n][k] : Wr[n-256][k].
__global__ __launch_bounds__(256) void k0_cast(
    const float* __restrict__ Wl, const float* __restrict__ Wr,
    unsigned short* __restrict__ Wb)
{
    const int idx = blockIdx.x * 256 + threadIdx.x;   // 32768 quads
    const int e = idx * 4;
    const int n = e >> 8, k = e & 255;
    const float* src = (n < 256) ? (Wl + (size_t)n * D + k)
                                 : (Wr + (size_t)(n - 256) * D + k);
    const float4 f = *(const float4*)src;
    ushort4 h;
    h.x = f2bf(f.x); h.y = f2bf(f.y); h.z = f2bf(f.z); h.w = f2bf(f.w);
    *(ushort4*)(Wb + (size_t)n * D + k) = h;
}

// K1 (MFMA): C[row,n] = sum_k Ae[row,k]*W'[n,k] + b'[n]; outputs bf16.
// Block: 16 m x 256 n (half = blockIdx&1), grid 512. 4 waves x 4 acc tiles.
// A: emb rows bf16 in LDS stride 264; B: row-major bf16 W == B-frag layout.
__global__ __launch_bounds__(256) void k1_mfma(
    const int* __restrict__ X, const float* __restrict__ emb,
    const unsigned short* __restrict__ Wb,
    const float* __restrict__ bl, const float* __restrict__ br,
    unsigned short* __restrict__ Xlb, unsigned short* __restrict__ Xrb)
{
    constexpr int LDA = 264;
    __shared__ unsigned short Asb[16 * LDA];   // 8448 B

    const int tid = threadIdx.x;
    const int rowBase = (blockIdx.x >> 1) * 16;
    const int half = blockIdx.x & 1;

    {
        const int r = tid >> 4;
        const int c0 = (tid & 15) * 16;
        const int tok = X[rowBase + r];
        const float* src = emb + (size_t)tok * D + c0;
        unsigned short* dst = Asb + r * LDA + c0;
#pragma unroll
        for (int j4 = 0; j4 < 4; ++j4) {
            const float4 f = ((const float4*)src)[j4];
            ushort4 h;
            h.x = f2bf(f.x); h.y = f2bf(f.y); h.z = f2bf(f.z); h.w = f2bf(f.w);
            ((ushort4*)dst)[j4] = h;
        }
    }
    __syncthreads();

    const int w  = tid >> 6;        // wave 0..3
    const int l  = tid & 63;
    const int lm = l & 15;
    const int lq = l >> 4;

    const unsigned short* aptr = Asb + lm * LDA + lq * 8;
    const int n_base = half * 256 + w * 64;
    const unsigned short* bptr = Wb + (size_t)(n_base + lm) * D + lq * 8;

    f32x4 acc[4];
#pragma unroll
    for (int t = 0; t < 4; ++t) acc[t] = (f32x4){0.f, 0.f, 0.f, 0.f};

#pragma unroll
    for (int ks = 0; ks < 8; ++ks) {
        const bf16x8 a = *(const bf16x8*)(aptr + ks * 32);
#pragma unroll
        for (int t = 0; t < 4; ++t) {
            const bf16x8 b = *(const bf16x8*)(bptr + (size_t)t * 16 * D + ks * 32);
            acc[t] = __builtin_amdgcn_mfma_f32_16x16x32_bf16(a, b, acc[t], 0, 0, 0);
        }
    }

    const float* __restrict__ bias = half ? br : bl;
    unsigned short* __restrict__ Obase = half ? Xrb : Xlb;
#pragma unroll
    for (int t = 0; t < 4; ++t) {
        const int col = w * 64 + t * 16 + lm;
        const float bv = bias[col];
#pragma unroll
        for (int i = 0; i < 4; ++i) {
            const int row = rowBase + lq * 4 + i;
            Obase[(size_t)row * D + col] = f2bf(acc[t][i] + bv);
        }
    }
}

// K2: pooled[b,d] = 0.5*( S*(sum_j xl + sum_i xr) + sum_{ij}|xl_j + xr_i| )
// bf16 inputs, fp32 LDS staging; 8 independent |.| accumulators (no serial
// dependency chain in the inner loop).
__global__ __launch_bounds__(256) void k2_pairsum(
    const unsigned short* __restrict__ Xlb, const unsigned short* __restrict__ Xrb,
    float* __restrict__ pooled)
{
    __shared__ float lxl[S * DC];   // [j][dl] : 8 KB
    __shared__ float lxr[S * DC];
    __shared__ float red[256];

    const int b   = blockIdx.x >> 4;
    const int dc  = blockIdx.x & 15;
    const int tid = threadIdx.x;
    const int dl  = tid & (DC - 1);
    const int ig  = tid >> 4;          // 0..15, 8 i's each

    const size_t base = (size_t)b * S * D + (size_t)dc * DC;
    {
        // 512 ushort4-chunks per array (j = c4>>2, df = c4&3), 2 per thread
#pragma unroll
        for (int t = 0; t < 2; ++t) {
            const int c4 = tid + t * 256;
            const int j = c4 >> 2, df = c4 & 3;
            const ushort4 hl = *(const ushort4*)(Xlb + base + (size_t)j * D + df * 4);
            const ushort4 hr = *(const ushort4*)(Xrb + base + (size_t)j * D + df * 4);
            float4 fl, fr;
            fl.x = bf2f(hl.x); fl.y = bf2f(hl.y); fl.z = bf2f(hl.z); fl.w = bf2f(hl.w);
            fr.x = bf2f(hr.x); fr.y = bf2f(hr.y); fr.z = bf2f(hr.z); fr.w = bf2f(hr.w);
            *(float4*)(lxl + j * DC + df * 4) = fl;
            *(float4*)(lxr + j * DC + df * 4) = fr;
        }
    }
    __syncthreads();

    float xr[8];
    float sr = 0.f;
#pragma unroll
    for (int u = 0; u < 8; ++u) {
        xr[u] = lxr[(ig * 8 + u) * DC + dl];
        sr += xr[u];
    }

    float sa[8];
#pragma unroll
    for (int u = 0; u < 8; ++u) sa[u] = 0.f;
    float sxl = 0.f;
#pragma unroll 4
    for (int j = 0; j < S; ++j) {
        const float x = lxl[j * DC + dl];
        sxl += x;
#pragma unroll
        for (int u = 0; u < 8; ++u)
            sa[u] += fabsf(x + xr[u]);     // 8 independent chains
    }
    float sabs = ((sa[0] + sa[1]) + (sa[2] + sa[3]))
               + ((sa[4] + sa[5]) + (sa[6] + sa[7]));

    red[tid] = sabs + (float)S * sr;
    __syncthreads();

    if (tid < DC) {
        float tot = 0.f;
#pragma unroll
        for (int g = 0; g < 16; ++g) tot += red[g * DC + tid];
        pooled[(size_t)b * D + (size_t)dc * DC + tid] =
            0.5f * ((float)S * sxl + tot);
    }
}

// K3: out[b,d] = sum_k pooled[b,k]*Wrn[d,k] + S*S*brn[d]
__global__ __launch_bounds__(256) void k3_out(
    const float* __restrict__ pooled, const float* __restrict__ Wrn,
    const float* __restrict__ brn, float* __restrict__ out)
{
    __shared__ float lp[D];
    __shared__ float red[256];
    const int bb = blockIdx.x >> 3;
    const int dc = blockIdx.x & 7;
    const int tid = threadIdx.x;
    lp[tid] = pooled[(size_t)bb * D + tid];
    __syncthreads();

    const int dl = tid & 31;
    const int kg = tid >> 5;
    const int d = dc * 32 + dl;
    const float4* __restrict__ w4 = (const float4*)(Wrn + (size_t)d * D) + kg * 8;
    const float4* __restrict__ p4 = (const float4*)lp + kg * 8;
    float acc = 0.f;
#pragma unroll
    for (int f = 0; f < 8; ++f) acc += dot4(w4[f], p4[f]);

    red[tid] = acc;
    __syncthreads();
    if (tid < 32) {
        float s = 0.f;
#pragma unroll
        for (int g = 0; g < 8; ++g) s += red[g * 32 + tid];
        out[(size_t)bb * D + dc * 32 + tid] = s + (float)(S * S) * brn[dc * 32 + tid];
    }
}

extern "C" void kernel_launch(void* const* d_in, const int* in_sizes, int n_in,
                              void* d_out, int out_size, void* d_ws, size_t ws_size,
                              hipStream_t stream) {
    const int*   X   = (const int*)d_in[0];
    const float* emb = (const float*)d_in[1];
    const float* Wl  = (const float*)d_in[2];
    const float* bl  = (const float*)d_in[3];
    const float* Wr  = (const float*)d_in[4];
    const float* br  = (const float*)d_in[5];
    const float* Wrn = (const float*)d_in[6];
    const float* brn = (const float*)d_in[7];
    float* out = (float*)d_out;

    const size_t NX = (size_t)B * S * D;            // 1M elems
    unsigned short* Xlb = (unsigned short*)d_ws;               // 2 MB
    unsigned short* Xrb = Xlb + NX;                            // 2 MB
    float* pooled = (float*)(Xrb + NX);                        // 32 KB
    unsigned short* Wb = (unsigned short*)(pooled + B * D);    // 256 KB

    k0_cast<<<128, 256, 0, stream>>>(Wl, Wr, Wb);
    k1_mfma<<<512, 256, 0, stream>>>(X, emb, Wb, bl, br, Xlb, Xrb);
    k2_pairsum<<<B * (D / DC), 256, 0, stream>>>(Xlb, Xrb, pooled);
    k3_out<<<B * 8, 256, 0, stream>>>(pooled, Wrn, brn, out);
}